// Round 12
// baseline (630.102 us; speedup 1.0000x reference)
//
#include <hip/hip_runtime.h>

typedef __bf16 bf16x8 __attribute__((ext_vector_type(8)));
typedef __bf16 bf16x4 __attribute__((ext_vector_type(4)));
typedef float  f32x4  __attribute__((ext_vector_type(4)));
typedef float  f32x16 __attribute__((ext_vector_type(16)));
typedef unsigned u32x4 __attribute__((ext_vector_type(4)));

#define LOG2E 1.4426950408889634f

__device__ __forceinline__ void gload16(const void* g, void* l) {
  __builtin_amdgcn_global_load_lds((const __attribute__((address_space(1))) void*)g,
                                   (__attribute__((address_space(3))) void*)l, 16, 0, 0);
}

__device__ __forceinline__ unsigned pk(float lo, float hi) {
  unsigned short lu = __builtin_bit_cast(unsigned short, (__bf16)lo);
  unsigned short hu = __builtin_bit_cast(unsigned short, (__bf16)hi);
  return (unsigned)lu | ((unsigned)hu << 16);
}

// ---------------- f32 -> bf16 elementwise convert (x) ----------------
__global__ __launch_bounds__(256) void cvt4(const float* __restrict__ in,
                                            __bf16* __restrict__ outp, int n4) {
  int i = blockIdx.x * blockDim.x + threadIdx.x;
  if (i < n4) {
    float4 v = ((const float4*)in)[i];
    bf16x4 o = { (__bf16)v.x, (__bf16)v.y, (__bf16)v.z, (__bf16)v.w };
    *(bf16x4*)(outp + (size_t)i * 4) = o;
  }
}

// ---------------- f32 [K,N] -> bf16 [N,K] transpose-convert ----------------
__global__ __launch_bounds__(256) void transcvt(const float* __restrict__ w,
                                                __bf16* __restrict__ wt,
                                                int K, int N) {
  __shared__ float tile[32][33];
  const int n0 = blockIdx.x * 32, k0 = blockIdx.y * 32;
  const int tx = threadIdx.x, ty = threadIdx.y;
#pragma unroll
  for (int i = 0; i < 4; ++i)
    tile[ty + i * 8][tx] = w[(size_t)(k0 + ty + i * 8) * N + n0 + tx];
  __syncthreads();
#pragma unroll
  for (int i = 0; i < 4; ++i)
    wt[(size_t)(n0 + ty + i * 8) * K + k0 + tx] = (__bf16)tile[tx][ty + i * 8];
}

// ---------------- bf16 GEMM, 256x256 tile, interleaved read||MFMA pipeline ---
// (unchanged from round 7: 8 waves, K-step 32, 4 LDS slots/matrix, both-sides
// bank swizzle, register one-ahead operand pipeline, counted vmcnt.)
template <int EPI, int NCOLS>
__global__ __launch_bounds__(512, 2)
void gemm_bt(const __bf16* __restrict__ A, const __bf16* __restrict__ Bt,
             const float* __restrict__ bias,
             __bf16* __restrict__ Qb, __bf16* __restrict__ Kb,
             __bf16* __restrict__ Vtb, float* __restrict__ Out) {
  constexpr int K = 2048;
  constexpr int NSTEP = K / 32;          // 64
  constexpr int NBX = NCOLS / 256;
  __shared__ __align__(16) __bf16 lds_[65536];   // 128 KiB
  __bf16* const As_ = lds_;                      // A slots: 4 x 8192 elems
  __bf16* const Bs_ = lds_ + 32768;              // B slots: 4 x 8192 elems
  const int tid = threadIdx.x, lane = tid & 63, w = tid >> 6;
  const int wr = w >> 2, wc = w & 3;
  const int l15 = lane & 15, g = lane >> 4;

  // XCD-aware swizzle (grid is a multiple of 8)
  const int nwg = (int)gridDim.x;
  const int flat = ((int)blockIdx.x & 7) * (nwg >> 3) + ((int)blockIdx.x >> 3);
  const int by = flat / NBX, bx = flat % NBX;

  const __bf16* Ab = A + (size_t)by * 256 * K;
  const __bf16* Bb = Bt + (size_t)bx * 256 * K;

  // staging: thread tid's 16B lands at LDS (row = idx>>2, chunk = tid&3);
  // source carries chunk (tid&3)^((row>>1)&3) = (tid&3)^((tid>>3)&3).
  const int gsw = (((tid & 3) ^ ((tid >> 3) & 3)) * 8);
  const __bf16* srcA[2];
  const __bf16* srcB[2];
#pragma unroll
  for (int c = 0; c < 2; ++c) {
    const int idx = c * 512 + tid;
    const int row = idx >> 2;
    srcA[c] = Ab + (size_t)row * K + gsw;
    srcB[c] = Bb + (size_t)row * K + gsw;
  }
  const int ldst = tid * 8;  // element offset within a slot (16B per thread)

  // read-side swizzled k-chunk (elements): g ^ ((row>>1)&3), row ≡ l15 (mod 8)
  const int csw = ((g ^ ((l15 >> 1) & 3)) * 8);
  const int aoff = (wr * 128 + l15) * 32 + csw;  // + i*512 for A frag i
  const int boff = (wc * 64 + l15) * 32 + csw;   // + i*512 for B frag i

  f32x4 acc[8][4] = {};

#define LDA(rs, i) (*(const bf16x8*)(As_ + (rs) + aoff + (i) * 512))
#define LDB(rs, i) (*(const bf16x8*)(Bs_ + (rs) + boff + (i) * 512))
#define ISSUE_A(jj) { const int s_ = ((jj) & 3) * 8192;                       \
    gload16(srcA[0] + (size_t)(jj) * 32, (void*)(As_ + s_ + ldst));           \
    gload16(srcA[1] + (size_t)(jj) * 32, (void*)(As_ + s_ + 4096 + ldst)); }
#define ISSUE_B(jj) { const int s_ = ((jj) & 3) * 8192;                       \
    gload16(srcB[0] + (size_t)(jj) * 32, (void*)(Bs_ + s_ + ldst));           \
    gload16(srcB[1] + (size_t)(jj) * 32, (void*)(Bs_ + s_ + 4096 + ldst)); }
#define VM8 asm volatile("s_waitcnt vmcnt(8)" ::: "memory")
#define VM4 asm volatile("s_waitcnt vmcnt(4)" ::: "memory")
#define VM0 asm volatile("s_waitcnt vmcnt(0)" ::: "memory")
#define VMN
#define MFMA8(p0, p1, bq, m0, m1)                                             \
  _Pragma("unroll")                                                           \
  for (int ni = 0; ni < 4; ++ni) {                                            \
    acc[m0][ni] = __builtin_amdgcn_mfma_f32_16x16x32_bf16(p0, bq[ni],         \
                                                          acc[m0][ni], 0,0,0);\
    acc[m1][ni] = __builtin_amdgcn_mfma_f32_16x16x32_bf16(p1, bq[ni],         \
                                                          acc[m1][ni], 0,0,0);\
  }

  // K-step: reads interleaved with MFMA clusters in one window; avC/bvC were
  // read one window ahead (prev step region B). 2 barriers per step.
#define KSTEP(j, ISS, VMW, RB, avC, avN, bvC, bvN) {                          \
    const int rs_ = ((j) & 3) * 8192;                                         \
    const int rn_ = (((j) + 1) & 3) * 8192;                                   \
    bf16x8 a2 = LDA(rs_, 2), a3 = LDA(rs_, 3);                                \
    MFMA8(avC[0], avC[1], bvC, 0, 1);                                         \
    bf16x8 a4 = LDA(rs_, 4), a5 = LDA(rs_, 5);                                \
    MFMA8(a2, a3, bvC, 2, 3);                                                 \
    if (ISS) ISSUE_A((j) + 3);                                                \
    bf16x8 a6 = LDA(rs_, 6), a7 = LDA(rs_, 7);                                \
    MFMA8(a4, a5, bvC, 4, 5);                                                 \
    if (ISS) ISSUE_B((j) + 3);                                                \
    VMW;                                                                      \
    __builtin_amdgcn_s_barrier();                                             \
    if (RB) {                                                                 \
      avN[0] = LDA(rn_, 0); avN[1] = LDA(rn_, 1);                             \
      bvN[0] = LDB(rn_, 0); bvN[1] = LDB(rn_, 1);                             \
      bvN[2] = LDB(rn_, 2); bvN[3] = LDB(rn_, 3);                             \
    }                                                                         \
    MFMA8(a6, a7, bvC, 6, 7);                                                 \
    __builtin_amdgcn_s_barrier();                                             \
  }

  bf16x8 avX[2], avY[2], bvX[4], bvY[4];

  // prologue: stage k-steps 0..2; land step 0; preload its first operands
  ISSUE_A(0); ISSUE_B(0);
  ISSUE_A(1); ISSUE_B(1);
  ISSUE_A(2); ISSUE_B(2);
  VM8;
  __builtin_amdgcn_s_barrier();
  avX[0] = LDA(0, 0); avX[1] = LDA(0, 1);
  bvX[0] = LDB(0, 0); bvX[1] = LDB(0, 1);
  bvX[2] = LDB(0, 2); bvX[3] = LDB(0, 3);

  for (int j = 0; j < NSTEP - 4; j += 2) {
    KSTEP(j,     true, VM8, true, avX, avY, bvX, bvY);
    KSTEP(j + 1, true, VM8, true, avY, avX, bvY, bvX);
  }
  KSTEP(NSTEP - 4, true,  VM8, true,  avX, avY, bvX, bvY);
  KSTEP(NSTEP - 3, false, VM4, true,  avY, avX, bvY, bvX);
  KSTEP(NSTEP - 2, false, VM0, true,  avX, avY, bvX, bvY);
  KSTEP(NSTEP - 1, false, VMN, false, avY, avX, bvY, bvX);

#undef KSTEP
#undef MFMA8
#undef ISSUE_A
#undef ISSUE_B
#undef LDA
#undef LDB

  // epilogue: C frag layout col = lane&15, row = (lane>>4)*4 + j (m89-verified)
  const int r0 = by * 256 + wr * 128 + (g << 2);
  const int c0 = bx * 256 + wc * 64 + l15;
#pragma unroll
  for (int ni = 0; ni < 4; ++ni) {
    const int c = c0 + ni * 16;
    const float bvs = bias[c];
    if constexpr (EPI == 0) {
      const int sel = c >> 11, cc = c & 2047, h = cc >> 7, d = cc & 127;
#pragma unroll
      for (int mi = 0; mi < 8; ++mi) {
        const int r = r0 + mi * 16;
        const int bb = r >> 11, t = r & 2047;
        if (sel == 2) {
          bf16x4 pv;
#pragma unroll
          for (int j = 0; j < 4; ++j) pv[j] = (__bf16)(acc[mi][ni][j] + bvs);
          *(bf16x4*)(Vtb + ((size_t)(bb * 16 + h) * 128 + d) * 2048 + t) = pv;
        } else {
          __bf16* dst = (sel == 0 ? Qb : Kb) + ((size_t)(bb * 16 + h) * 2048 + t) * 128 + d;
          const float sc = (sel == 0) ? 0.08838834764831845f : 1.0f;  // 1/sqrt(128)
#pragma unroll
          for (int j = 0; j < 4; ++j)
            dst[(size_t)j * 128] = (__bf16)((acc[mi][ni][j] + bvs) * sc);
        }
      }
    } else {
#pragma unroll
      for (int mi = 0; mi < 8; ++mi) {
        const int r = r0 + mi * 16;
#pragma unroll
        for (int j = 0; j < 4; ++j)
          Out[(size_t)(r + j) * NCOLS + c] = acc[mi][ni][j] + bvs;
      }
    }
  }
}

// ---------------- causal flash attention: 8-warp 32x32, 2 blocks/CU ---------
// grid 512, ONE item per block (no persistent loop). Block b < 256 -> item b,
// else item 767-b: the (b, b+256) pair lands on the same CU under round-robin
// dispatch and always sums to 36 KV-tiles -> balanced. 64KB LDS, lb(512,4)
// => 2 independent blocks/CU whose barrier phases anti-align (softmax of one
// overlaps MFMA/LDS of the other).
__global__ __launch_bounds__(512, 4)
void attn_fwd(const __bf16* __restrict__ Qb, const __bf16* __restrict__ Kb,
              const __bf16* __restrict__ Vtb, __bf16* __restrict__ Yb) {
  __shared__ __align__(16) char lds[65536];  // 2 x (K 16KB + V^T 16KB)
  const int tid = threadIdx.x;
  const int lane = tid & 63, w = tid >> 6;   // 8 warps
  const int l31 = lane & 31, hi = lane >> 5;
  const int kx = (l31 & 7) << 4;             // read-side XOR swizzle

  const int b = (int)blockIdx.x;
  const int item = (b < 256) ? b : 767 - b;
  const int qb = 7 - (item >> 6);            // heavy items on low blockIdx
  const int bh = item & 63;
  const int bidx = bh >> 4, h = bh & 15;
  const int nt = (qb + 1) * 4;

  const __bf16* Qh = Qb + ((size_t)bh * 2048 + qb * 256) * 128;
  const __bf16* Kh = Kb + (size_t)bh * 2048 * 128;
  const __bf16* Vh = Vtb + (size_t)bh * 128 * 2048;

  // Q fragments: B-operand rows, lane holds Q[q=l31, d = ds*16 + hi*8 + e]
  bf16x8 qf[8];
  {
    const __bf16* qrow = Qh + (size_t)(w * 32 + l31) * 128 + hi * 8;
#pragma unroll
    for (int ds = 0; ds < 8; ++ds) qf[ds] = *(const bf16x8*)(qrow + ds * 16);
  }

  // prologue: stage tile 0 -> buf 0
  {
    uint4 kr[2], vr[2];
#pragma unroll
    for (int c = 0; c < 2; ++c) {
      const int idx = c * 512 + tid;
      kr[c] = *(const uint4*)(Kh + (size_t)(idx >> 4) * 128 + (idx & 15) * 8);
      vr[c] = *(const uint4*)(Vh + (size_t)(idx >> 3) * 2048 + (idx & 7) * 8);
    }
    char* K0 = lds;
    char* V0 = lds + 16384;
#pragma unroll
    for (int c = 0; c < 2; ++c) {
      const int idx = c * 512 + tid;
      { const int row = idx >> 4, colB = (idx & 15) * 16;
        *(uint4*)(K0 + row * 256 + (colB ^ ((row & 7) << 4))) = kr[c]; }
      { const int row = idx >> 3, colB = (idx & 7) * 16;
        *(uint4*)(V0 + row * 128 + (colB ^ ((row & 7) << 4))) = vr[c]; }
    }
    __syncthreads();
  }

  f32x16 accO[4] = {};        // O^T[d = db*32 + reg-row, q = l31]
  float mL = -3.0e38f, lsum = 0.f;
  const int qg  = qb * 256 + w * 32 + l31;  // this lane's q (S^T column)
  const int qwb = qb * 256 + w * 32;        // warp's min q

  for (int t = 0; t < nt; ++t) {
    const int kv0 = t * 64;
    char* Kc = lds + (t & 1) * 32768;
    char* Vc = Kc + 16384;
    const bool pf = (t + 1 < nt);
    uint4 kr[2], vr[2];
    if (pf) {  // T14: issue next tile's loads now, write to LDS after compute
      const int kvn = kv0 + 64;
#pragma unroll
      for (int c = 0; c < 2; ++c) {
        const int idx = c * 512 + tid;
        kr[c] = *(const uint4*)(Kh + (size_t)(kvn + (idx >> 4)) * 128 + (idx & 15) * 8);
        vr[c] = *(const uint4*)(Vh + (size_t)(idx >> 3) * 2048 + kvn + (idx & 7) * 8);
      }
    }

    // S^T = K Q^T : col = q = l31, row(reg r) = (r&3)+8*(r>>2)+4*hi (+32*frag)
    f32x16 s0 = {}, s1 = {};
    __builtin_amdgcn_s_setprio(1);
#pragma unroll
    for (int ds = 0; ds < 8; ++ds) {
      const int cb = (ds * 32 + hi * 16) ^ kx;
      bf16x8 k0 = *(const bf16x8*)(Kc + l31 * 256 + cb);
      bf16x8 k1 = *(const bf16x8*)(Kc + (32 + l31) * 256 + cb);
      s0 = __builtin_amdgcn_mfma_f32_32x32x16_bf16(k0, qf[ds], s0, 0, 0, 0);
      s1 = __builtin_amdgcn_mfma_f32_32x32x16_bf16(k1, qf[ds], s1, 0, 0, 0);
    }
    __builtin_amdgcn_s_setprio(0);

    // log2 domain + causal mask (diagonal tiles only)
    f32x16 a0, a1;
#pragma unroll
    for (int r = 0; r < 16; ++r) { a0[r] = s0[r] * LOG2E; a1[r] = s1[r] * LOG2E; }
    if (kv0 + 63 > qwb) {
#pragma unroll
      for (int r = 0; r < 16; ++r) {
        const int kvr = kv0 + (r & 3) + 8 * (r >> 2) + 4 * hi;
        if (kvr > qg)      a0[r] = -1.0e38f;
        if (kvr + 32 > qg) a1[r] = -1.0e38f;
      }
    }

    // row max: 31 local + 1 shfl (partner holds other 32 kv of this q-row)
    float pm = a0[0];
#pragma unroll
    for (int r = 1; r < 16; ++r) pm = fmaxf(pm, a0[r]);
#pragma unroll
    for (int r = 0; r < 16; ++r) pm = fmaxf(pm, a1[r]);
    pm = fmaxf(pm, __shfl_xor(pm, 32, 64));

    // T13 defer-max: skip O rescale unless max grew past threshold
    if (!__all(pm - mL <= 11.5f)) {
      const float mn = fmaxf(mL, pm);
      const float corr = exp2f(mL - mn);
      mL = mn;
      lsum *= corr;
#pragma unroll
      for (int db = 0; db < 4; ++db)
#pragma unroll
        for (int r = 0; r < 16; ++r) accO[db][r] *= corr;
    }

    float p[32];
    float rs = 0.f;
#pragma unroll
    for (int r = 0; r < 16; ++r) { p[r] = exp2f(a0[r] - mL); rs += p[r]; }
#pragma unroll
    for (int r = 0; r < 16; ++r) { p[16 + r] = exp2f(a1[r] - mL); rs += p[16 + r]; }
    rs += __shfl_xor(rs, 32, 64);
    lsum += rs;

    // pack P -> PV B-frags: pa[ks] elem e = P[q=l31, kv = ks*16 + hi*8 + e]
    bf16x8 pa[4];
#pragma unroll
    for (int f = 0; f < 2; ++f) {
      unsigned wv[8];
#pragma unroll
      for (int i = 0; i < 8; ++i)
        wv[i] = pk(p[f * 16 + 2 * i], p[f * 16 + 2 * i + 1]);
      // exchange complementary quads with partner lane (l ^ 32)
      const unsigned x0 = (unsigned)__shfl_xor((int)(hi ? wv[0] : wv[2]), 32, 64);
      const unsigned x1 = (unsigned)__shfl_xor((int)(hi ? wv[1] : wv[3]), 32, 64);
      const unsigned x2 = (unsigned)__shfl_xor((int)(hi ? wv[4] : wv[6]), 32, 64);
      const unsigned x3 = (unsigned)__shfl_xor((int)(hi ? wv[5] : wv[7]), 32, 64);
      u32x4 A, B;
      A[0] = hi ? x0 : wv[0];  A[1] = hi ? x1 : wv[1];
      A[2] = hi ? wv[2] : x0;  A[3] = hi ? wv[3] : x1;
      B[0] = hi ? x2 : wv[4];  B[1] = hi ? x3 : wv[5];
      B[2] = hi ? wv[6] : x2;  B[3] = hi ? wv[7] : x3;
      pa[f * 2 + 0] = __builtin_bit_cast(bf16x8, A);
      pa[f * 2 + 1] = __builtin_bit_cast(bf16x8, B);
    }

    // O^T += V^T P^T : A = V^T rows (d), B = pa, acc col = q (lane-local)
    __builtin_amdgcn_s_setprio(1);
#pragma unroll
    for (int ks = 0; ks < 4; ++ks) {
      const int cb = (ks * 32 + hi * 16) ^ kx;
#pragma unroll
      for (int db = 0; db < 4; ++db) {
        bf16x8 vf = *(const bf16x8*)(Vc + (db * 32 + l31) * 128 + cb);
        accO[db] = __builtin_amdgcn_mfma_f32_32x32x16_bf16(vf, pa[ks], accO[db], 0, 0, 0);
      }
    }
    __builtin_amdgcn_s_setprio(0);

    if (pf) {  // publish prefetched tile into the other buffer
      char* Kn = lds + ((t + 1) & 1) * 32768;
      char* Vn = Kn + 16384;
#pragma unroll
      for (int c = 0; c < 2; ++c) {
        const int idx = c * 512 + tid;
        { const int row = idx >> 4, colB = (idx & 15) * 16;
          *(uint4*)(Kn + row * 256 + (colB ^ ((row & 7) << 4))) = kr[c]; }
        { const int row = idx >> 3, colB = (idx & 7) * 16;
          *(uint4*)(Vn + row * 128 + (colB ^ ((row & 7) << 4))) = vr[c]; }
      }
    }
    __syncthreads();
  }

  // epilogue: Y[b, q, h*128 + d] = O^T[d, q] / l   (d = db*32 + 8j + 4hi + i)
  const float rl = 1.0f / lsum;
  __bf16* Yw = Yb + ((size_t)bidx * 2048 + qg) * 2048 + h * 128;
#pragma unroll
  for (int db = 0; db < 4; ++db)
#pragma unroll
    for (int j = 0; j < 4; ++j) {
      bf16x4 o;
#pragma unroll
      for (int i = 0; i < 4; ++i) o[i] = (__bf16)(accO[db][4 * j + i] * rl);
      *(bf16x4*)(Yw + db * 32 + 8 * j + 4 * hi) = o;
    }
}

// ---------------- launch ----------------
extern "C" void kernel_launch(void* const* d_in, const int* in_sizes, int n_in,
                              void* d_out, int out_size, void* d_ws, size_t ws_size,
                              hipStream_t stream) {
  const float* x      = (const float*)d_in[0];
  const float* w_attn = (const float*)d_in[1];
  const float* b_attn = (const float*)d_in[2];
  const float* w_proj = (const float*)d_in[3];
  const float* b_proj = (const float*)d_in[4];
  float* out = (float*)d_out;

  __bf16* Qb  = (__bf16*)d_ws;                 // [B,H,T,D] (pre-scaled 1/sqrt(D))
  __bf16* Kb  = Qb  + (size_t)16777216;        // [B,H,T,D]
  __bf16* Vtb = Kb  + (size_t)16777216;        // [B,H,D,T]
  __bf16* XYb = Vtb + (size_t)16777216;        // x_bf16, later y_bf16 [B,T,C]
  __bf16* Wt  = XYb + (size_t)16777216;        // w_attn^T / w_proj^T

  cvt4<<<dim3(16384), dim3(256), 0, stream>>>(x, XYb, 4194304);
  transcvt<<<dim3(192, 64), dim3(32, 8), 0, stream>>>(w_attn, Wt, 2048, 6144);
  gemm_bt<0, 6144><<<dim3(768), dim3(512), 0, stream>>>(XYb, Wt, b_attn,
                                                        Qb, Kb, Vtb, nullptr);
  transcvt<<<dim3(64, 64), dim3(32, 8), 0, stream>>>(w_proj, Wt, 2048, 2048);
  attn_fwd<<<dim3(512), dim3(512), 0, stream>>>(Qb, Kb, Vtb, XYb);
  gemm_bt<1, 2048><<<dim3(256), dim3(512), 0, stream>>>(XYb, Wt, b_proj,
                                                        nullptr, nullptr, nullptr, out);
}

// Round 13
// 622.552 us; speedup vs baseline: 1.0121x; 1.0121x over previous
//
#include <hip/hip_runtime.h>

typedef __bf16 bf16x8 __attribute__((ext_vector_type(8)));
typedef __bf16 bf16x4 __attribute__((ext_vector_type(4)));
typedef float  f32x4  __attribute__((ext_vector_type(4)));
typedef float  f32x16 __attribute__((ext_vector_type(16)));
typedef unsigned u32x4 __attribute__((ext_vector_type(4)));

#define LOG2E 1.4426950408889634f

__device__ __forceinline__ void gload16(const void* g, void* l) {
  __builtin_amdgcn_global_load_lds((const __attribute__((address_space(1))) void*)g,
                                   (__attribute__((address_space(3))) void*)l, 16, 0, 0);
}

__device__ __forceinline__ unsigned pk(float lo, float hi) {
  unsigned short lu = __builtin_bit_cast(unsigned short, (__bf16)lo);
  unsigned short hu = __builtin_bit_cast(unsigned short, (__bf16)hi);
  return (unsigned)lu | ((unsigned)hu << 16);
}

// ---------------- f32 -> bf16 elementwise convert (x) ----------------
__global__ __launch_bounds__(256) void cvt4(const float* __restrict__ in,
                                            __bf16* __restrict__ outp, int n4) {
  int i = blockIdx.x * blockDim.x + threadIdx.x;
  if (i < n4) {
    float4 v = ((const float4*)in)[i];
    bf16x4 o = { (__bf16)v.x, (__bf16)v.y, (__bf16)v.z, (__bf16)v.w };
    *(bf16x4*)(outp + (size_t)i * 4) = o;
  }
}

// ---------------- f32 [K,N] -> bf16 [N,K] transpose-convert ----------------
__global__ __launch_bounds__(256) void transcvt(const float* __restrict__ w,
                                                __bf16* __restrict__ wt,
                                                int K, int N) {
  __shared__ float tile[32][33];
  const int n0 = blockIdx.x * 32, k0 = blockIdx.y * 32;
  const int tx = threadIdx.x, ty = threadIdx.y;
#pragma unroll
  for (int i = 0; i < 4; ++i)
    tile[ty + i * 8][tx] = w[(size_t)(k0 + ty + i * 8) * N + n0 + tx];
  __syncthreads();
#pragma unroll
  for (int i = 0; i < 4; ++i)
    wt[(size_t)(n0 + ty + i * 8) * K + k0 + tx] = (__bf16)tile[tx][ty + i * 8];
}

// ---------------- bf16 GEMM, 256x256 tile, interleaved read||MFMA pipeline ---
// (unchanged from round 7: 8 waves, K-step 32, 4 LDS slots/matrix, both-sides
// bank swizzle, register one-ahead operand pipeline, counted vmcnt.)
template <int EPI, int NCOLS>
__global__ __launch_bounds__(512, 2)
void gemm_bt(const __bf16* __restrict__ A, const __bf16* __restrict__ Bt,
             const float* __restrict__ bias,
             __bf16* __restrict__ Qb, __bf16* __restrict__ Kb,
             __bf16* __restrict__ Vtb, float* __restrict__ Out) {
  constexpr int K = 2048;
  constexpr int NSTEP = K / 32;          // 64
  constexpr int NBX = NCOLS / 256;
  __shared__ __align__(16) __bf16 lds_[65536];   // 128 KiB
  __bf16* const As_ = lds_;                      // A slots: 4 x 8192 elems
  __bf16* const Bs_ = lds_ + 32768;              // B slots: 4 x 8192 elems
  const int tid = threadIdx.x, lane = tid & 63, w = tid >> 6;
  const int wr = w >> 2, wc = w & 3;
  const int l15 = lane & 15, g = lane >> 4;

  // XCD-aware swizzle (grid is a multiple of 8)
  const int nwg = (int)gridDim.x;
  const int flat = ((int)blockIdx.x & 7) * (nwg >> 3) + ((int)blockIdx.x >> 3);
  const int by = flat / NBX, bx = flat % NBX;

  const __bf16* Ab = A + (size_t)by * 256 * K;
  const __bf16* Bb = Bt + (size_t)bx * 256 * K;

  // staging: thread tid's 16B lands at LDS (row = idx>>2, chunk = tid&3);
  // source carries chunk (tid&3)^((row>>1)&3) = (tid&3)^((tid>>3)&3).
  const int gsw = (((tid & 3) ^ ((tid >> 3) & 3)) * 8);
  const __bf16* srcA[2];
  const __bf16* srcB[2];
#pragma unroll
  for (int c = 0; c < 2; ++c) {
    const int idx = c * 512 + tid;
    const int row = idx >> 2;
    srcA[c] = Ab + (size_t)row * K + gsw;
    srcB[c] = Bb + (size_t)row * K + gsw;
  }
  const int ldst = tid * 8;  // element offset within a slot (16B per thread)

  // read-side swizzled k-chunk (elements): g ^ ((row>>1)&3), row ≡ l15 (mod 8)
  const int csw = ((g ^ ((l15 >> 1) & 3)) * 8);
  const int aoff = (wr * 128 + l15) * 32 + csw;  // + i*512 for A frag i
  const int boff = (wc * 64 + l15) * 32 + csw;   // + i*512 for B frag i

  f32x4 acc[8][4] = {};

#define LDA(rs, i) (*(const bf16x8*)(As_ + (rs) + aoff + (i) * 512))
#define LDB(rs, i) (*(const bf16x8*)(Bs_ + (rs) + boff + (i) * 512))
#define ISSUE_A(jj) { const int s_ = ((jj) & 3) * 8192;                       \
    gload16(srcA[0] + (size_t)(jj) * 32, (void*)(As_ + s_ + ldst));           \
    gload16(srcA[1] + (size_t)(jj) * 32, (void*)(As_ + s_ + 4096 + ldst)); }
#define ISSUE_B(jj) { const int s_ = ((jj) & 3) * 8192;                       \
    gload16(srcB[0] + (size_t)(jj) * 32, (void*)(Bs_ + s_ + ldst));           \
    gload16(srcB[1] + (size_t)(jj) * 32, (void*)(Bs_ + s_ + 4096 + ldst)); }
#define VM8 asm volatile("s_waitcnt vmcnt(8)" ::: "memory")
#define VM4 asm volatile("s_waitcnt vmcnt(4)" ::: "memory")
#define VM0 asm volatile("s_waitcnt vmcnt(0)" ::: "memory")
#define VMN
#define MFMA8(p0, p1, bq, m0, m1)                                             \
  _Pragma("unroll")                                                           \
  for (int ni = 0; ni < 4; ++ni) {                                            \
    acc[m0][ni] = __builtin_amdgcn_mfma_f32_16x16x32_bf16(p0, bq[ni],         \
                                                          acc[m0][ni], 0,0,0);\
    acc[m1][ni] = __builtin_amdgcn_mfma_f32_16x16x32_bf16(p1, bq[ni],         \
                                                          acc[m1][ni], 0,0,0);\
  }

  // K-step: reads interleaved with MFMA clusters in one window; avC/bvC were
  // read one window ahead (prev step region B). 2 barriers per step.
#define KSTEP(j, ISS, VMW, RB, avC, avN, bvC, bvN) {                          \
    const int rs_ = ((j) & 3) * 8192;                                         \
    const int rn_ = (((j) + 1) & 3) * 8192;                                   \
    bf16x8 a2 = LDA(rs_, 2), a3 = LDA(rs_, 3);                                \
    MFMA8(avC[0], avC[1], bvC, 0, 1);                                         \
    bf16x8 a4 = LDA(rs_, 4), a5 = LDA(rs_, 5);                                \
    MFMA8(a2, a3, bvC, 2, 3);                                                 \
    if (ISS) ISSUE_A((j) + 3);                                                \
    bf16x8 a6 = LDA(rs_, 6), a7 = LDA(rs_, 7);                                \
    MFMA8(a4, a5, bvC, 4, 5);                                                 \
    if (ISS) ISSUE_B((j) + 3);                                                \
    VMW;                                                                      \
    __builtin_amdgcn_s_barrier();                                             \
    if (RB) {                                                                 \
      avN[0] = LDA(rn_, 0); avN[1] = LDA(rn_, 1);                             \
      bvN[0] = LDB(rn_, 0); bvN[1] = LDB(rn_, 1);                             \
      bvN[2] = LDB(rn_, 2); bvN[3] = LDB(rn_, 3);                             \
    }                                                                         \
    MFMA8(a6, a7, bvC, 6, 7);                                                 \
    __builtin_amdgcn_s_barrier();                                             \
  }

  bf16x8 avX[2], avY[2], bvX[4], bvY[4];

  // prologue: stage k-steps 0..2; land step 0; preload its first operands
  ISSUE_A(0); ISSUE_B(0);
  ISSUE_A(1); ISSUE_B(1);
  ISSUE_A(2); ISSUE_B(2);
  VM8;
  __builtin_amdgcn_s_barrier();
  avX[0] = LDA(0, 0); avX[1] = LDA(0, 1);
  bvX[0] = LDB(0, 0); bvX[1] = LDB(0, 1);
  bvX[2] = LDB(0, 2); bvX[3] = LDB(0, 3);

  for (int j = 0; j < NSTEP - 4; j += 2) {
    KSTEP(j,     true, VM8, true, avX, avY, bvX, bvY);
    KSTEP(j + 1, true, VM8, true, avY, avX, bvY, bvX);
  }
  KSTEP(NSTEP - 4, true,  VM8, true,  avX, avY, bvX, bvY);
  KSTEP(NSTEP - 3, false, VM4, true,  avY, avX, bvY, bvX);
  KSTEP(NSTEP - 2, false, VM0, true,  avX, avY, bvX, bvY);
  KSTEP(NSTEP - 1, false, VMN, false, avY, avX, bvY, bvX);

#undef KSTEP
#undef MFMA8
#undef ISSUE_A
#undef ISSUE_B
#undef LDA
#undef LDB

  // epilogue: C frag layout col = lane&15, row = (lane>>4)*4 + j (m89-verified)
  const int r0 = by * 256 + wr * 128 + (g << 2);
  const int c0 = bx * 256 + wc * 64 + l15;
#pragma unroll
  for (int ni = 0; ni < 4; ++ni) {
    const int c = c0 + ni * 16;
    const float bvs = bias[c];
    if constexpr (EPI == 0) {
      const int sel = c >> 11, cc = c & 2047, h = cc >> 7, d = cc & 127;
#pragma unroll
      for (int mi = 0; mi < 8; ++mi) {
        const int r = r0 + mi * 16;
        const int bb = r >> 11, t = r & 2047;
        if (sel == 2) {
          bf16x4 pv;
#pragma unroll
          for (int j = 0; j < 4; ++j) pv[j] = (__bf16)(acc[mi][ni][j] + bvs);
          *(bf16x4*)(Vtb + ((size_t)(bb * 16 + h) * 128 + d) * 2048 + t) = pv;
        } else {
          __bf16* dst = (sel == 0 ? Qb : Kb) + ((size_t)(bb * 16 + h) * 2048 + t) * 128 + d;
          const float sc = (sel == 0) ? 0.08838834764831845f : 1.0f;  // 1/sqrt(128)
#pragma unroll
          for (int j = 0; j < 4; ++j)
            dst[(size_t)j * 128] = (__bf16)((acc[mi][ni][j] + bvs) * sc);
        }
      }
    } else {
#pragma unroll
      for (int mi = 0; mi < 8; ++mi) {
        const int r = r0 + mi * 16;
#pragma unroll
        for (int j = 0; j < 4; ++j)
          Out[(size_t)(r + j) * NCOLS + c] = acc[mi][ni][j] + bvs;
      }
    }
  }
}

// ---------------- causal flash attention: 8-warp 32x32, 2 blocks/CU ---------
// grid 512, ONE item per block (no persistent loop). Block b < 256 -> item b,
// else item 767-b: the (b, b+256) pair lands on the same CU under round-robin
// dispatch and always sums to 36 KV-tiles -> balanced. 64KB LDS, lb(512,4)
// => 2 independent blocks/CU whose barrier phases anti-align (softmax of one
// overlaps MFMA/LDS of the other).
__global__ __launch_bounds__(512, 4)
void attn_fwd(const __bf16* __restrict__ Qb, const __bf16* __restrict__ Kb,
              const __bf16* __restrict__ Vtb, __bf16* __restrict__ Yb) {
  __shared__ __align__(16) char lds[65536];  // 2 x (K 16KB + V^T 16KB)
  const int tid = threadIdx.x;
  const int lane = tid & 63, w = tid >> 6;   // 8 warps
  const int l31 = lane & 31, hi = lane >> 5;
  const int kx = (l31 & 7) << 4;             // read-side XOR swizzle

  const int b = (int)blockIdx.x;
  const int item = (b < 256) ? b : 767 - b;
  const int qb = 7 - (item >> 6);            // heavy items on low blockIdx
  const int bh = item & 63;
  const int bidx = bh >> 4, h = bh & 15;
  const int nt = (qb + 1) * 4;

  const __bf16* Qh = Qb + ((size_t)bh * 2048 + qb * 256) * 128;
  const __bf16* Kh = Kb + (size_t)bh * 2048 * 128;
  const __bf16* Vh = Vtb + (size_t)bh * 128 * 2048;

  // Q fragments: B-operand rows, lane holds Q[q=l31, d = ds*16 + hi*8 + e]
  bf16x8 qf[8];
  {
    const __bf16* qrow = Qh + (size_t)(w * 32 + l31) * 128 + hi * 8;
#pragma unroll
    for (int ds = 0; ds < 8; ++ds) qf[ds] = *(const bf16x8*)(qrow + ds * 16);
  }

  // prologue: stage tile 0 -> buf 0
  {
    uint4 kr[2], vr[2];
#pragma unroll
    for (int c = 0; c < 2; ++c) {
      const int idx = c * 512 + tid;
      kr[c] = *(const uint4*)(Kh + (size_t)(idx >> 4) * 128 + (idx & 15) * 8);
      vr[c] = *(const uint4*)(Vh + (size_t)(idx >> 3) * 2048 + (idx & 7) * 8);
    }
    char* K0 = lds;
    char* V0 = lds + 16384;
#pragma unroll
    for (int c = 0; c < 2; ++c) {
      const int idx = c * 512 + tid;
      { const int row = idx >> 4, colB = (idx & 15) * 16;
        *(uint4*)(K0 + row * 256 + (colB ^ ((row & 7) << 4))) = kr[c]; }
      { const int row = idx >> 3, colB = (idx & 7) * 16;
        *(uint4*)(V0 + row * 128 + (colB ^ ((row & 7) << 4))) = vr[c]; }
    }
    __syncthreads();
  }

  f32x16 accO[4] = {};        // O^T[d = db*32 + reg-row, q = l31]
  float mL = -3.0e38f, lsum = 0.f;
  const int qg  = qb * 256 + w * 32 + l31;  // this lane's q (S^T column)
  const int qwb = qb * 256 + w * 32;        // warp's min q

  for (int t = 0; t < nt; ++t) {
    const int kv0 = t * 64;
    char* Kc = lds + (t & 1) * 32768;
    char* Vc = Kc + 16384;
    const bool pf = (t + 1 < nt);
    uint4 kr[2], vr[2];
    if (pf) {  // T14: issue next tile's loads now, write to LDS after compute
      const int kvn = kv0 + 64;
#pragma unroll
      for (int c = 0; c < 2; ++c) {
        const int idx = c * 512 + tid;
        kr[c] = *(const uint4*)(Kh + (size_t)(kvn + (idx >> 4)) * 128 + (idx & 15) * 8);
        vr[c] = *(const uint4*)(Vh + (size_t)(idx >> 3) * 2048 + kvn + (idx & 7) * 8);
      }
    }

    // S^T = K Q^T : col = q = l31, row(reg r) = (r&3)+8*(r>>2)+4*hi (+32*frag)
    f32x16 s0 = {}, s1 = {};
    __builtin_amdgcn_s_setprio(1);
#pragma unroll
    for (int ds = 0; ds < 8; ++ds) {
      const int cb = (ds * 32 + hi * 16) ^ kx;
      bf16x8 k0 = *(const bf16x8*)(Kc + l31 * 256 + cb);
      bf16x8 k1 = *(const bf16x8*)(Kc + (32 + l31) * 256 + cb);
      s0 = __builtin_amdgcn_mfma_f32_32x32x16_bf16(k0, qf[ds], s0, 0, 0, 0);
      s1 = __builtin_amdgcn_mfma_f32_32x32x16_bf16(k1, qf[ds], s1, 0, 0, 0);
    }
    __builtin_amdgcn_s_setprio(0);

    // log2 domain + causal mask (diagonal tiles only)
    f32x16 a0, a1;
#pragma unroll
    for (int r = 0; r < 16; ++r) { a0[r] = s0[r] * LOG2E; a1[r] = s1[r] * LOG2E; }
    if (kv0 + 63 > qwb) {
#pragma unroll
      for (int r = 0; r < 16; ++r) {
        const int kvr = kv0 + (r & 3) + 8 * (r >> 2) + 4 * hi;
        if (kvr > qg)      a0[r] = -1.0e38f;
        if (kvr + 32 > qg) a1[r] = -1.0e38f;
      }
    }

    // row max: 31 local + 1 shfl (partner holds other 32 kv of this q-row)
    float pm = a0[0];
#pragma unroll
    for (int r = 1; r < 16; ++r) pm = fmaxf(pm, a0[r]);
#pragma unroll
    for (int r = 0; r < 16; ++r) pm = fmaxf(pm, a1[r]);
    pm = fmaxf(pm, __shfl_xor(pm, 32, 64));

    // T13 defer-max: skip O rescale unless max grew past threshold
    if (!__all(pm - mL <= 11.5f)) {
      const float mn = fmaxf(mL, pm);
      const float corr = exp2f(mL - mn);
      mL = mn;
      lsum *= corr;
#pragma unroll
      for (int db = 0; db < 4; ++db)
#pragma unroll
        for (int r = 0; r < 16; ++r) accO[db][r] *= corr;
    }

    float p[32];
    float rs = 0.f;
#pragma unroll
    for (int r = 0; r < 16; ++r) { p[r] = exp2f(a0[r] - mL); rs += p[r]; }
#pragma unroll
    for (int r = 0; r < 16; ++r) { p[16 + r] = exp2f(a1[r] - mL); rs += p[16 + r]; }
    rs += __shfl_xor(rs, 32, 64);
    lsum += rs;

    // pack P -> PV B-frags: pa[ks] elem e = P[q=l31, kv = ks*16 + hi*8 + e]
    bf16x8 pa[4];
#pragma unroll
    for (int f = 0; f < 2; ++f) {
      unsigned wv[8];
#pragma unroll
      for (int i = 0; i < 8; ++i)
        wv[i] = pk(p[f * 16 + 2 * i], p[f * 16 + 2 * i + 1]);
      // exchange complementary quads with partner lane (l ^ 32)
      const unsigned x0 = (unsigned)__shfl_xor((int)(hi ? wv[0] : wv[2]), 32, 64);
      const unsigned x1 = (unsigned)__shfl_xor((int)(hi ? wv[1] : wv[3]), 32, 64);
      const unsigned x2 = (unsigned)__shfl_xor((int)(hi ? wv[4] : wv[6]), 32, 64);
      const unsigned x3 = (unsigned)__shfl_xor((int)(hi ? wv[5] : wv[7]), 32, 64);
      u32x4 A, B;
      A[0] = hi ? x0 : wv[0];  A[1] = hi ? x1 : wv[1];
      A[2] = hi ? wv[2] : x0;  A[3] = hi ? wv[3] : x1;
      B[0] = hi ? x2 : wv[4];  B[1] = hi ? x3 : wv[5];
      B[2] = hi ? wv[6] : x2;  B[3] = hi ? wv[7] : x3;
      pa[f * 2 + 0] = __builtin_bit_cast(bf16x8, A);
      pa[f * 2 + 1] = __builtin_bit_cast(bf16x8, B);
    }

    // O^T += V^T P^T : A = V^T rows (d), B = pa, acc col = q (lane-local)
    __builtin_amdgcn_s_setprio(1);
#pragma unroll
    for (int ks = 0; ks < 4; ++ks) {
      const int cb = (ks * 32 + hi * 16) ^ kx;
#pragma unroll
      for (int db = 0; db < 4; ++db) {
        bf16x8 vf = *(const bf16x8*)(Vc + (db * 32 + l31) * 128 + cb);
        accO[db] = __builtin_amdgcn_mfma_f32_32x32x16_bf16(vf, pa[ks], accO[db], 0, 0, 0);
      }
    }
    __builtin_amdgcn_s_setprio(0);

    if (pf) {  // publish prefetched tile into the other buffer
      char* Kn = lds + ((t + 1) & 1) * 32768;
      char* Vn = Kn + 16384;
#pragma unroll
      for (int c = 0; c < 2; ++c) {
        const int idx = c * 512 + tid;
        { const int row = idx >> 4, colB = (idx & 15) * 16;
          *(uint4*)(Kn + row * 256 + (colB ^ ((row & 7) << 4))) = kr[c]; }
        { const int row = idx >> 3, colB = (idx & 7) * 16;
          *(uint4*)(Vn + row * 128 + (colB ^ ((row & 7) << 4))) = vr[c]; }
      }
    }
    __syncthreads();
  }

  // epilogue: Y[b, q, h*128 + d] = O^T[d, q] / l   (d = db*32 + 8j + 4hi + i)
  const float rl = 1.0f / lsum;
  __bf16* Yw = Yb + ((size_t)bidx * 2048 + qg) * 2048 + h * 128;
#pragma unroll
  for (int db = 0; db < 4; ++db)
#pragma unroll
    for (int j = 0; j < 4; ++j) {
      bf16x4 o;
#pragma unroll
      for (int i = 0; i < 4; ++i) o[i] = (__bf16)(accO[db][4 * j + i] * rl);
      *(bf16x4*)(Yw + db * 32 + 8 * j + 4 * hi) = o;
    }
}

// ---------------- launch ----------------
extern "C" void kernel_launch(void* const* d_in, const int* in_sizes, int n_in,
                              void* d_out, int out_size, void* d_ws, size_t ws_size,
                              hipStream_t stream) {
  const float* x      = (const float*)d_in[0];
  const float* w_attn = (const float*)d_in[1];
  const float* b_attn = (const float*)d_in[2];
  const float* w_proj = (const float*)d_in[3];
  const float* b_proj = (const float*)d_in[4];
  float* out = (float*)d_out;

  __bf16* Qb  = (__bf16*)d_ws;                 // [B,H,T,D] (pre-scaled 1/sqrt(D))
  __bf16* Kb  = Qb  + (size_t)16777216;        // [B,H,T,D]
  __bf16* Vtb = Kb  + (size_t)16777216;        // [B,H,D,T]
  __bf16* XYb = Vtb + (size_t)16777216;        // x_bf16, later y_bf16 [B,T,C]
  __bf16* Wt  = XYb + (size_t)16777216;        // w_attn^T / w_proj^T

  cvt4<<<dim3(16384), dim3(256), 0, stream>>>(x, XYb, 4194304);
  transcvt<<<dim3(192, 64), dim3(32, 8), 0, stream>>>(w_attn, Wt, 2048, 6144);
  gemm_bt<0, 6144><<<dim3(768), dim3(512), 0, stream>>>(XYb, Wt, b_attn,
                                                        Qb, Kb, Vtb, nullptr);
  transcvt<<<dim3(64, 64), dim3(32, 8), 0, stream>>>(w_proj, Wt, 2048, 2048);
  attn_fwd<<<dim3(512), dim3(512), 0, stream>>>(Qb, Kb, Vtb, XYb);
  gemm_bt<1, 2048><<<dim3(256), dim3(512), 0, stream>>>(XYb, Wt, b_proj,
                                                        nullptr, nullptr, nullptr, out);
}

// Round 14
// 413.771 us; speedup vs baseline: 1.5228x; 1.5046x over previous
//
#include <hip/hip_runtime.h>

typedef __bf16 bf16x8 __attribute__((ext_vector_type(8)));
typedef __bf16 bf16x4 __attribute__((ext_vector_type(4)));
typedef float  f32x4  __attribute__((ext_vector_type(4)));
typedef float  f32x16 __attribute__((ext_vector_type(16)));
typedef unsigned u32x4 __attribute__((ext_vector_type(4)));

#define LOG2E 1.4426950408889634f

__device__ __forceinline__ void gload16(const void* g, void* l) {
  __builtin_amdgcn_global_load_lds((const __attribute__((address_space(1))) void*)g,
                                   (__attribute__((address_space(3))) void*)l, 16, 0, 0);
}

__device__ __forceinline__ unsigned pk(float lo, float hi) {
  unsigned short lu = __builtin_bit_cast(unsigned short, (__bf16)lo);
  unsigned short hu = __builtin_bit_cast(unsigned short, (__bf16)hi);
  return (unsigned)lu | ((unsigned)hu << 16);
}

// ---------------- f32 -> bf16 elementwise convert (x) ----------------
__global__ __launch_bounds__(256) void cvt4(const float* __restrict__ in,
                                            __bf16* __restrict__ outp, int n4) {
  int i = blockIdx.x * blockDim.x + threadIdx.x;
  if (i < n4) {
    float4 v = ((const float4*)in)[i];
    bf16x4 o = { (__bf16)v.x, (__bf16)v.y, (__bf16)v.z, (__bf16)v.w };
    *(bf16x4*)(outp + (size_t)i * 4) = o;
  }
}

// ---------------- f32 [K,N] -> bf16 [N,K] transpose-convert ----------------
__global__ __launch_bounds__(256) void transcvt(const float* __restrict__ w,
                                                __bf16* __restrict__ wt,
                                                int K, int N) {
  __shared__ float tile[32][33];
  const int n0 = blockIdx.x * 32, k0 = blockIdx.y * 32;
  const int tx = threadIdx.x, ty = threadIdx.y;
#pragma unroll
  for (int i = 0; i < 4; ++i)
    tile[ty + i * 8][tx] = w[(size_t)(k0 + ty + i * 8) * N + n0 + tx];
  __syncthreads();
#pragma unroll
  for (int i = 0; i < 4; ++i)
    wt[(size_t)(n0 + ty + i * 8) * K + k0 + tx] = (__bf16)tile[tx][ty + i * 8];
}

// ---------------- bf16 GEMM, 256x256 tile, interleaved read||MFMA pipeline ---
// (unchanged from round 7: 8 waves, K-step 32, 4 LDS slots/matrix, both-sides
// bank swizzle, register one-ahead operand pipeline, counted vmcnt.)
template <int EPI, int NCOLS>
__global__ __launch_bounds__(512, 2)
void gemm_bt(const __bf16* __restrict__ A, const __bf16* __restrict__ Bt,
             const float* __restrict__ bias,
             __bf16* __restrict__ Qb, __bf16* __restrict__ Kb,
             __bf16* __restrict__ Vtb, float* __restrict__ Out) {
  constexpr int K = 2048;
  constexpr int NSTEP = K / 32;          // 64
  constexpr int NBX = NCOLS / 256;
  __shared__ __align__(16) __bf16 lds_[65536];   // 128 KiB
  __bf16* const As_ = lds_;                      // A slots: 4 x 8192 elems
  __bf16* const Bs_ = lds_ + 32768;              // B slots: 4 x 8192 elems
  const int tid = threadIdx.x, lane = tid & 63, w = tid >> 6;
  const int wr = w >> 2, wc = w & 3;
  const int l15 = lane & 15, g = lane >> 4;

  // XCD-aware swizzle (grid is a multiple of 8)
  const int nwg = (int)gridDim.x;
  const int flat = ((int)blockIdx.x & 7) * (nwg >> 3) + ((int)blockIdx.x >> 3);
  const int by = flat / NBX, bx = flat % NBX;

  const __bf16* Ab = A + (size_t)by * 256 * K;
  const __bf16* Bb = Bt + (size_t)bx * 256 * K;

  // staging: thread tid's 16B lands at LDS (row = idx>>2, chunk = tid&3);
  // source carries chunk (tid&3)^((row>>1)&3) = (tid&3)^((tid>>3)&3).
  const int gsw = (((tid & 3) ^ ((tid >> 3) & 3)) * 8);
  const __bf16* srcA[2];
  const __bf16* srcB[2];
#pragma unroll
  for (int c = 0; c < 2; ++c) {
    const int idx = c * 512 + tid;
    const int row = idx >> 2;
    srcA[c] = Ab + (size_t)row * K + gsw;
    srcB[c] = Bb + (size_t)row * K + gsw;
  }
  const int ldst = tid * 8;  // element offset within a slot (16B per thread)

  // read-side swizzled k-chunk (elements): g ^ ((row>>1)&3), row ≡ l15 (mod 8)
  const int csw = ((g ^ ((l15 >> 1) & 3)) * 8);
  const int aoff = (wr * 128 + l15) * 32 + csw;  // + i*512 for A frag i
  const int boff = (wc * 64 + l15) * 32 + csw;   // + i*512 for B frag i

  f32x4 acc[8][4] = {};

#define LDA(rs, i) (*(const bf16x8*)(As_ + (rs) + aoff + (i) * 512))
#define LDB(rs, i) (*(const bf16x8*)(Bs_ + (rs) + boff + (i) * 512))
#define ISSUE_A(jj) { const int s_ = ((jj) & 3) * 8192;                       \
    gload16(srcA[0] + (size_t)(jj) * 32, (void*)(As_ + s_ + ldst));           \
    gload16(srcA[1] + (size_t)(jj) * 32, (void*)(As_ + s_ + 4096 + ldst)); }
#define ISSUE_B(jj) { const int s_ = ((jj) & 3) * 8192;                       \
    gload16(srcB[0] + (size_t)(jj) * 32, (void*)(Bs_ + s_ + ldst));           \
    gload16(srcB[1] + (size_t)(jj) * 32, (void*)(Bs_ + s_ + 4096 + ldst)); }
#define VM8 asm volatile("s_waitcnt vmcnt(8)" ::: "memory")
#define VM4 asm volatile("s_waitcnt vmcnt(4)" ::: "memory")
#define VM0 asm volatile("s_waitcnt vmcnt(0)" ::: "memory")
#define VMN
#define MFMA8(p0, p1, bq, m0, m1)                                             \
  _Pragma("unroll")                                                           \
  for (int ni = 0; ni < 4; ++ni) {                                            \
    acc[m0][ni] = __builtin_amdgcn_mfma_f32_16x16x32_bf16(p0, bq[ni],         \
                                                          acc[m0][ni], 0,0,0);\
    acc[m1][ni] = __builtin_amdgcn_mfma_f32_16x16x32_bf16(p1, bq[ni],         \
                                                          acc[m1][ni], 0,0,0);\
  }

  // K-step: reads interleaved with MFMA clusters in one window; avC/bvC were
  // read one window ahead (prev step region B). 2 barriers per step.
#define KSTEP(j, ISS, VMW, RB, avC, avN, bvC, bvN) {                          \
    const int rs_ = ((j) & 3) * 8192;                                         \
    const int rn_ = (((j) + 1) & 3) * 8192;                                   \
    bf16x8 a2 = LDA(rs_, 2), a3 = LDA(rs_, 3);                                \
    MFMA8(avC[0], avC[1], bvC, 0, 1);                                         \
    bf16x8 a4 = LDA(rs_, 4), a5 = LDA(rs_, 5);                                \
    MFMA8(a2, a3, bvC, 2, 3);                                                 \
    if (ISS) ISSUE_A((j) + 3);                                                \
    bf16x8 a6 = LDA(rs_, 6), a7 = LDA(rs_, 7);                                \
    MFMA8(a4, a5, bvC, 4, 5);                                                 \
    if (ISS) ISSUE_B((j) + 3);                                                \
    VMW;                                                                      \
    __builtin_amdgcn_s_barrier();                                             \
    if (RB) {                                                                 \
      avN[0] = LDA(rn_, 0); avN[1] = LDA(rn_, 1);                             \
      bvN[0] = LDB(rn_, 0); bvN[1] = LDB(rn_, 1);                             \
      bvN[2] = LDB(rn_, 2); bvN[3] = LDB(rn_, 3);                             \
    }                                                                         \
    MFMA8(a6, a7, bvC, 6, 7);                                                 \
    __builtin_amdgcn_s_barrier();                                             \
  }

  bf16x8 avX[2], avY[2], bvX[4], bvY[4];

  // prologue: stage k-steps 0..2; land step 0; preload its first operands
  ISSUE_A(0); ISSUE_B(0);
  ISSUE_A(1); ISSUE_B(1);
  ISSUE_A(2); ISSUE_B(2);
  VM8;
  __builtin_amdgcn_s_barrier();
  avX[0] = LDA(0, 0); avX[1] = LDA(0, 1);
  bvX[0] = LDB(0, 0); bvX[1] = LDB(0, 1);
  bvX[2] = LDB(0, 2); bvX[3] = LDB(0, 3);

  for (int j = 0; j < NSTEP - 4; j += 2) {
    KSTEP(j,     true, VM8, true, avX, avY, bvX, bvY);
    KSTEP(j + 1, true, VM8, true, avY, avX, bvY, bvX);
  }
  KSTEP(NSTEP - 4, true,  VM8, true,  avX, avY, bvX, bvY);
  KSTEP(NSTEP - 3, false, VM4, true,  avY, avX, bvY, bvX);
  KSTEP(NSTEP - 2, false, VM0, true,  avX, avY, bvX, bvY);
  KSTEP(NSTEP - 1, false, VMN, false, avY, avX, bvY, bvX);

#undef KSTEP
#undef MFMA8
#undef ISSUE_A
#undef ISSUE_B
#undef LDA
#undef LDB

  // epilogue: C frag layout col = lane&15, row = (lane>>4)*4 + j (m89-verified)
  const int r0 = by * 256 + wr * 128 + (g << 2);
  const int c0 = bx * 256 + wc * 64 + l15;
#pragma unroll
  for (int ni = 0; ni < 4; ++ni) {
    const int c = c0 + ni * 16;
    const float bvs = bias[c];
    if constexpr (EPI == 0) {
      const int sel = c >> 11, cc = c & 2047, h = cc >> 7, d = cc & 127;
#pragma unroll
      for (int mi = 0; mi < 8; ++mi) {
        const int r = r0 + mi * 16;
        const int bb = r >> 11, t = r & 2047;
        if (sel == 2) {
          bf16x4 pv;
#pragma unroll
          for (int j = 0; j < 4; ++j) pv[j] = (__bf16)(acc[mi][ni][j] + bvs);
          *(bf16x4*)(Vtb + ((size_t)(bb * 16 + h) * 128 + d) * 2048 + t) = pv;
        } else {
          __bf16* dst = (sel == 0 ? Qb : Kb) + ((size_t)(bb * 16 + h) * 2048 + t) * 128 + d;
          // Q pre-scale folds 1/sqrt(128) AND log2(e) so attn softmax works
          // directly in the log2 domain (saves a VALU pass per sub-tile).
          const float sc = (sel == 0)
              ? (0.08838834764831845f * 1.4426950408889634f) : 1.0f;
#pragma unroll
          for (int j = 0; j < 4; ++j)
            dst[(size_t)j * 128] = (__bf16)((acc[mi][ni][j] + bvs) * sc);
        }
      }
    } else {
#pragma unroll
      for (int mi = 0; mi < 8; ++mi) {
        const int r = r0 + mi * 16;
#pragma unroll
        for (int j = 0; j < 4; ++j)
          Out[(size_t)(r + j) * NCOLS + c] = acc[mi][ni][j] + bvs;
      }
    }
  }
}

// ---------------- causal flash attention: 8-warp 32x32, KVBLK=128 windows ---
// Persistent grid 256, lb(512,2) (VGPR cap 256 — the r8 spill is gone).
// LDS 128KB: dbuf x (K[128][128] + V^T[128][128]) bf16, nibble XOR swizzle
// ((row&15)<<4) -> all K/V frag reads <=2-way (free). Staging via
// global_load_lds with pre-swizzled SOURCE chunks (linear LDS dest), counted
// vmcnt(8). Two 64-kv sub-tiles per barrier window -> wider warp drift.
__global__ __launch_bounds__(512, 2)
void attn_fwd(const __bf16* __restrict__ Qb, const __bf16* __restrict__ Kb,
              const __bf16* __restrict__ Vtb, __bf16* __restrict__ Yb) {
  __shared__ __align__(16) char lds[131072];  // 2 x (K 32KB + V^T 32KB)
  const int tid = threadIdx.x;
  const int lane = tid & 63, w = tid >> 6;    // 8 warps
  const int l31 = lane & 31, hi = lane >> 5;
  const int kxn = (l31 & 15) << 4;            // read-side XOR swizzle (nibble)

  // staging constants: thread covers LDS chunks L = i*512+tid (16B each);
  // row = L>>4 = i*32 + (tid>>4), chunk = tid&15; source chunk' = chunk^(row&15)
  // = (tid&15)^((tid>>4)&15) — i-invariant.
  const int rowb = tid >> 4;
  const int ch8  = (((tid & 15) ^ (rowb & 15)) * 8);  // element offset
  const int dsto = tid * 16;                          // byte offset per stripe

  const int G = (int)gridDim.x;
  for (int rr = 0;; ++rr) {
    const int pos = (rr & 1) ? (G - 1 - (int)blockIdx.x) : (int)blockIdx.x;
    const int item = rr * G + pos;
    if (item >= 512) break;
    const int qb = 7 - (item >> 6);           // heavy first
    const int bh = item & 63;
    const int bidx = bh >> 4, h = bh & 15;
    const int nt2 = (qb + 1) * 2;             // 128-kv windows

    const __bf16* Qh = Qb + ((size_t)bh * 2048 + qb * 256) * 128;
    const __bf16* Kh = Kb + (size_t)bh * 2048 * 128;
    const __bf16* Vh = Vtb + (size_t)bh * 128 * 2048;
    const __bf16* pKs = Kh + rowb * 128 + ch8;
    const __bf16* pVs = Vh + (size_t)rowb * 2048 + ch8;

#define ISSUEW(tw) { char* bp_ = lds + ((tw) & 1) * 65536;                    \
    _Pragma("unroll")                                                         \
    for (int i_ = 0; i_ < 4; ++i_) {                                          \
      gload16(pKs + (size_t)(tw) * 16384 + i_ * 4096,                         \
              bp_ + i_ * 8192 + dsto);                                        \
      gload16(pVs + (size_t)(tw) * 128 + (size_t)i_ * 65536,                  \
              bp_ + 32768 + i_ * 8192 + dsto);                                \
    } }

    ISSUEW(0);  // start window-0 DMA before anything else

    // Q fragments: B-operand rows, lane holds Q[q=l31, d = ds*16 + hi*8 + e]
    bf16x8 qf[8];
    {
      const __bf16* qrow = Qh + (size_t)(w * 32 + l31) * 128 + hi * 8;
#pragma unroll
      for (int ds = 0; ds < 8; ++ds) qf[ds] = *(const bf16x8*)(qrow + ds * 16);
    }

    f32x16 accO[4] = {};        // O^T[d = db*32 + reg-row, q = l31]
    float mL = -3.0e38f, lsum = 0.f;
    const int qg  = qb * 256 + w * 32 + l31;  // this lane's q (S^T column)
    const int qwb = qb * 256 + w * 32;        // warp's min q

    for (int t2 = 0; t2 < nt2; ++t2) {
      char* Kc = lds + (t2 & 1) * 65536;
      char* Vc = Kc + 32768;
      if (t2 + 1 < nt2) {
        ISSUEW(t2 + 1);                        // prefetch into other buffer
        asm volatile("s_waitcnt vmcnt(8)" ::: "memory");  // this window landed
      } else {
        asm volatile("s_waitcnt vmcnt(0)" ::: "memory");
      }
      __builtin_amdgcn_s_barrier();            // all waves' DMA visible

#pragma unroll
      for (int s = 0; s < 2; ++s) {
        const int kv0 = t2 * 128 + s * 64;
        const char* Ks = Kc + s * 16384;

        // S^T = K Q^T (log2-domain: Q pre-scaled by 1/sqrt(D)*log2e)
        f32x16 s0 = {}, s1 = {};
        __builtin_amdgcn_s_setprio(1);
#pragma unroll
        for (int ds = 0; ds < 8; ++ds) {
          const int cb = (ds * 32 + hi * 16) ^ kxn;
          bf16x8 k0 = *(const bf16x8*)(Ks + l31 * 256 + cb);
          bf16x8 k1 = *(const bf16x8*)(Ks + (32 + l31) * 256 + cb);
          s0 = __builtin_amdgcn_mfma_f32_32x32x16_bf16(k0, qf[ds], s0, 0, 0, 0);
          s1 = __builtin_amdgcn_mfma_f32_32x32x16_bf16(k1, qf[ds], s1, 0, 0, 0);
        }
        __builtin_amdgcn_s_setprio(0);

        // causal mask (diagonal sub-tiles only)
        if (kv0 + 63 > qwb) {
#pragma unroll
          for (int r = 0; r < 16; ++r) {
            const int kvr = kv0 + (r & 3) + 8 * (r >> 2) + 4 * hi;
            if (kvr > qg)      s0[r] = -1.0e38f;
            if (kvr + 32 > qg) s1[r] = -1.0e38f;
          }
        }

        // row max: 31 local + 1 shfl
        float pm = s0[0];
#pragma unroll
        for (int r = 1; r < 16; ++r) pm = fmaxf(pm, s0[r]);
#pragma unroll
        for (int r = 0; r < 16; ++r) pm = fmaxf(pm, s1[r]);
        pm = fmaxf(pm, __shfl_xor(pm, 32, 64));

        // T13 defer-max (threshold in log2 units)
        if (!__all(pm - mL <= 11.5f)) {
          const float mn = fmaxf(mL, pm);
          const float corr = exp2f(mL - mn);
          mL = mn;
          lsum *= corr;
#pragma unroll
          for (int db = 0; db < 4; ++db)
#pragma unroll
            for (int r = 0; r < 16; ++r) accO[db][r] *= corr;
        }

        float p[32];
        float rs = 0.f;
#pragma unroll
        for (int r = 0; r < 16; ++r) { p[r] = exp2f(s0[r] - mL); rs += p[r]; }
#pragma unroll
        for (int r = 0; r < 16; ++r) { p[16 + r] = exp2f(s1[r] - mL); rs += p[16 + r]; }
        rs += __shfl_xor(rs, 32, 64);
        lsum += rs;

        // pack P -> PV B-frags: pa[ks] elem e = P[q=l31, kv = ks*16 + hi*8 + e]
        bf16x8 pa[4];
#pragma unroll
        for (int f = 0; f < 2; ++f) {
          unsigned wv[8];
#pragma unroll
          for (int i = 0; i < 8; ++i)
            wv[i] = pk(p[f * 16 + 2 * i], p[f * 16 + 2 * i + 1]);
          const unsigned x0 = (unsigned)__shfl_xor((int)(hi ? wv[0] : wv[2]), 32, 64);
          const unsigned x1 = (unsigned)__shfl_xor((int)(hi ? wv[1] : wv[3]), 32, 64);
          const unsigned x2 = (unsigned)__shfl_xor((int)(hi ? wv[4] : wv[6]), 32, 64);
          const unsigned x3 = (unsigned)__shfl_xor((int)(hi ? wv[5] : wv[7]), 32, 64);
          u32x4 A, B;
          A[0] = hi ? x0 : wv[0];  A[1] = hi ? x1 : wv[1];
          A[2] = hi ? wv[2] : x0;  A[3] = hi ? wv[3] : x1;
          B[0] = hi ? x2 : wv[4];  B[1] = hi ? x3 : wv[5];
          B[2] = hi ? wv[6] : x2;  B[3] = hi ? wv[7] : x3;
          pa[f * 2 + 0] = __builtin_bit_cast(bf16x8, A);
          pa[f * 2 + 1] = __builtin_bit_cast(bf16x8, B);
        }

        // O^T += V^T P^T
        __builtin_amdgcn_s_setprio(1);
#pragma unroll
        for (int ks = 0; ks < 4; ++ks) {
          const int cb = (s * 128 + ks * 32 + hi * 16) ^ kxn;
#pragma unroll
          for (int db = 0; db < 4; ++db) {
            bf16x8 vf = *(const bf16x8*)(Vc + (db * 32 + l31) * 256 + cb);
            accO[db] = __builtin_amdgcn_mfma_f32_32x32x16_bf16(vf, pa[ks],
                                                               accO[db], 0, 0, 0);
          }
        }
        __builtin_amdgcn_s_setprio(0);
      }
      __builtin_amdgcn_s_barrier();  // readers of this buffer done
    }
#undef ISSUEW

    // epilogue: Y[b, q, h*128 + d] = O^T[d, q] / l   (d = db*32 + 8j + 4hi + i)
    const float rl = 1.0f / lsum;
    __bf16* Yw = Yb + ((size_t)bidx * 2048 + qg) * 2048 + h * 128;
#pragma unroll
    for (int db = 0; db < 4; ++db)
#pragma unroll
      for (int j = 0; j < 4; ++j) {
        bf16x4 o;
#pragma unroll
        for (int i = 0; i < 4; ++i) o[i] = (__bf16)(accO[db][4 * j + i] * rl);
        *(bf16x4*)(Yw + db * 32 + 8 * j + 4 * hi) = o;
      }
  }
}

// ---------------- launch ----------------
extern "C" void kernel_launch(void* const* d_in, const int* in_sizes, int n_in,
                              void* d_out, int out_size, void* d_ws, size_t ws_size,
                              hipStream_t stream) {
  const float* x      = (const float*)d_in[0];
  const float* w_attn = (const float*)d_in[1];
  const float* b_attn = (const float*)d_in[2];
  const float* w_proj = (const float*)d_in[3];
  const float* b_proj = (const float*)d_in[4];
  float* out = (float*)d_out;

  __bf16* Qb  = (__bf16*)d_ws;                 // [B,H,T,D] (pre-scaled 1/sqrt(D)*log2e)
  __bf16* Kb  = Qb  + (size_t)16777216;        // [B,H,T,D]
  __bf16* Vtb = Kb  + (size_t)16777216;        // [B,H,D,T]
  __bf16* XYb = Vtb + (size_t)16777216;        // x_bf16, later y_bf16 [B,T,C]
  __bf16* Wt  = XYb + (size_t)16777216;        // w_attn^T / w_proj^T

  cvt4<<<dim3(16384), dim3(256), 0, stream>>>(x, XYb, 4194304);
  transcvt<<<dim3(192, 64), dim3(32, 8), 0, stream>>>(w_attn, Wt, 2048, 6144);
  gemm_bt<0, 6144><<<dim3(768), dim3(512), 0, stream>>>(XYb, Wt, b_attn,
                                                        Qb, Kb, Vtb, nullptr);
  transcvt<<<dim3(64, 64), dim3(32, 8), 0, stream>>>(w_proj, Wt, 2048, 2048);
  attn_fwd<<<dim3(256), dim3(512), 0, stream>>>(Qb, Kb, Vtb, XYb);
  gemm_bt<1, 2048><<<dim3(256), dim3(512), 0, stream>>>(XYb, Wt, b_proj,
                                                        nullptr, nullptr, nullptr, out);
}